// Round 18
// baseline (445.614 us; speedup 1.0000x reference)
//
#include <hip/hip_runtime.h>
#include <math.h>

// ---- problem constants ----
#define NB   64      // batch / scenarios
#define NN   512     // nodes
#define FIN  64      // feature dim (IN == HID)
#define EE   16384   // edges per scenario
#define H0S  4160    // HID*IN + HID
#define H1S  130     // OUT*HID + OUT
#define M0   12480   // 3*H0S
#define M1   390     // 3*H1S
#define GINK 4096    // TOPK*IN

typedef __attribute__((ext_vector_type(8))) short bf16x8;
typedef __attribute__((ext_vector_type(4))) float f32x4;

__device__ __forceinline__ float wred_sum(float v) {
  #pragma unroll
  for (int off = 32; off; off >>= 1) v += __shfl_down(v, off);
  return v;
}
__device__ __forceinline__ float wall_sum(float v) {
  #pragma unroll
  for (int off = 32; off; off >>= 1) v += __shfl_xor(v, off);
  return v;
}
__device__ __forceinline__ float sigm(float x) { return 1.f / (1.f + expf(-x)); }
__device__ __forceinline__ unsigned short f2bfu(float f) {
  unsigned int u = __float_as_uint(f);
  return (unsigned short)((u + 0x7fffu + ((u >> 16) & 1u)) >> 16);
}
// split a,b into packed hi bf16 pair and lo (residual) bf16 pair
__device__ __forceinline__ void split2(float a, float b,
                                       unsigned int& hi, unsigned int& lo) {
  unsigned short ha = f2bfu(a), hb = f2bfu(b);
  float ra = a - __uint_as_float((unsigned int)ha << 16);
  float rb = b - __uint_as_float((unsigned int)hb << 16);
  hi = (unsigned int)ha | ((unsigned int)hb << 16);
  lo = (unsigned int)f2bfu(ra) | ((unsigned int)f2bfu(rb) << 16);
}

#if __has_builtin(__builtin_amdgcn_global_load_lds)
#define HAVE_GLL 1
// async 16B global->LDS: lane l loads its per-lane global addr into
// wave-uniform LDS base + l*16
__device__ __forceinline__ void gload_lds16(const void* g, void* l) {
  __builtin_amdgcn_global_load_lds(
      (const __attribute__((address_space(1))) unsigned int*)g,
      (__attribute__((address_space(3))) unsigned int*)l, 16, 0, 0);
}
#else
#define HAVE_GLL 0
#endif

// ------------------------------------------------------------
// summarize body: y = h@pn (4-row ILP), in-register top-64
// (desc, min-idx tie), Zt[e][b]=(h*tanh(y))[sel]. 256 threads.
// ------------------------------------------------------------
__device__ __forceinline__ void sum_body(
    const float* __restrict__ h, const float* __restrict__ p,
    float* __restrict__ Zt, int b,
    float* yv, int* si, float* st) {
  const int tid = threadIdx.x;
  const int ln = tid & 63, wv = tid >> 6;
  float pv = p[ln];
  float s = wall_sum(pv * pv);
  float pn = pv / (sqrtf(s) + 1e-8f);
  const float* hb = h + (size_t)b * NN * FIN;
  for (int n0 = wv * 128; n0 < wv * 128 + 128; n0 += 4) {
    float a0 = hb[(n0 + 0) * FIN + ln] * pn;
    float a1 = hb[(n0 + 1) * FIN + ln] * pn;
    float a2 = hb[(n0 + 2) * FIN + ln] * pn;
    float a3 = hb[(n0 + 3) * FIN + ln] * pn;
    a0 = wred_sum(a0); a1 = wred_sum(a1);
    a2 = wred_sum(a2); a3 = wred_sum(a3);
    if (ln == 0) {
      yv[n0] = a0; yv[n0 + 1] = a1; yv[n0 + 2] = a2; yv[n0 + 3] = a3;
    }
  }
  __syncthreads();
  if (wv == 0) {
    float rv[8];
    #pragma unroll
    for (int j = 0; j < 8; ++j) rv[j] = yv[j * 64 + ln];
    for (int t = 0; t < 64; ++t) {
      float bv = rv[0]; int bj = 0;
      #pragma unroll
      for (int j = 1; j < 8; ++j) if (rv[j] > bv) { bv = rv[j]; bj = j; }
      int bn = bj * 64 + ln;
      #pragma unroll
      for (int off = 1; off < 64; off <<= 1) {
        float ov = __shfl_xor(bv, off); int on = __shfl_xor(bn, off);
        if (ov > bv || (ov == bv && on < bn)) { bv = ov; bn = on; }
      }
      if (ln == 0) { si[t] = bn; st[t] = tanhf(bv); }
      #pragma unroll
      for (int j = 0; j < 8; ++j) if (bn == j * 64 + ln) rv[j] = -3.4e38f;
    }
  }
  __syncthreads();
  for (int t = wv * 16; t < wv * 16 + 16; ++t) {
    int n = si[t]; float sc = st[t];
    Zt[(size_t)(t * 64 + ln) * NB + b] = hb[n * FIN + ln] * sc;
  }
}

// ------------------------------------------------------------
// k_misc: [0,64) deg/dinv (ILP x4) | [64,128) summarize0
//         [128,640) zero A | [640,738) gh1 rows
//         [738,13218) gh0 mat-vec — ROW PER BLOCK via async
//           global_load_lds staging.
// ------------------------------------------------------------
__global__ __launch_bounds__(256) void k_misc(
    const float* __restrict__ Whh1, const float* __restrict__ bhh1,
    const float* __restrict__ W1,   const float* __restrict__ b1,
    const int* __restrict__ ei, const float* __restrict__ ew,
    const float* __restrict__ x, const float* __restrict__ p0,
    float* __restrict__ gh1, float* __restrict__ A,
    float* __restrict__ dinv, float* __restrict__ Zt0,
    const float* __restrict__ Whh0, const float* __restrict__ bhh0,
    const float* __restrict__ W0,   const float* __restrict__ b0,
    float* __restrict__ gh0) {
  __shared__ float rowb[4096];
  __shared__ float smem[512];
  __shared__ int   ssel[64];
  __shared__ float sst[64];
  const int bid = blockIdx.x, tid = threadIdx.x;
  const int lane = tid & 63, wv = tid >> 6;
  if (bid < 64) {
    const int b = bid;
    smem[tid] = 1.0f; smem[tid + 256] = 1.0f;
    __syncthreads();
    const int* colp = ei + (size_t)b * 2 * EE + EE;
    const float* ewp = ew + (size_t)b * EE;
    for (int e = tid; e < EE; e += 1024) {
      int   c0 = colp[e],       c1 = colp[e + 256];
      int   c2 = colp[e + 512], c3 = colp[e + 768];
      float w0 = ewp[e],        w1 = ewp[e + 256];
      float w2 = ewp[e + 512],  w3 = ewp[e + 768];
      atomicAdd(&smem[c0], w0); atomicAdd(&smem[c1], w1);
      atomicAdd(&smem[c2], w2); atomicAdd(&smem[c3], w3);
    }
    __syncthreads();
    dinv[b * NN + tid]       = rsqrtf(smem[tid]);
    dinv[b * NN + tid + 256] = rsqrtf(smem[tid + 256]);
  } else if (bid < 128) {
    sum_body(x, p0, Zt0, bid - 64, smem, ssel, sst);
  } else if (bid < 640) {
    float4* Az = (float4*)A + (size_t)(bid - 128) * 8192;
    #pragma unroll 8
    for (int i = 0; i < 32; ++i) Az[i * 256 + tid] = make_float4(0.f, 0.f, 0.f, 0.f);
  } else if (bid < 738) {
    const int r = (bid - 640) * 4 + wv;
    if (r < M1) {
      const float* Ar = Whh1 + (size_t)r * H1S;
      float acc = Ar[lane] * W1[lane] + Ar[64 + lane] * W1[64 + lane];
      if (lane < 2) acc += Ar[128 + lane] * b1[lane];
      acc = wred_sum(acc);
      if (lane == 0) gh1[r] = acc + bhh1[r];
    }
  } else {
    const int r = bid - 738;
    const float* Ar = Whh0 + (size_t)r * H0S;
    float acc;
#if HAVE_GLL
    #pragma unroll
    for (int i = 0; i < 4; ++i) {
      const int c = (i * 4 + wv) * 64;            // uint4 chunk base
      gload_lds16((const uint4*)Ar + c + lane, (uint4*)rowb + c);
    }
    __syncthreads();                               // drains vmcnt
    const float4* R4 = (const float4*)rowb;
    const float4* W4 = (const float4*)W0;
    float4 a0 = R4[tid],       a1 = R4[256 + tid];
    float4 a2 = R4[512 + tid], a3 = R4[768 + tid];
    float4 v0 = W4[tid],       v1 = W4[256 + tid];
    float4 v2 = W4[512 + tid], v3 = W4[768 + tid];
    acc = a0.x * v0.x + a0.y * v0.y + a0.z * v0.z + a0.w * v0.w
        + a1.x * v1.x + a1.y * v1.y + a1.z * v1.z + a1.w * v1.w
        + a2.x * v2.x + a2.y * v2.y + a2.z * v2.z + a2.w * v2.w
        + a3.x * v3.x + a3.y * v3.y + a3.z * v3.z + a3.w * v3.w;
#else
    const float4* Ar4 = (const float4*)Ar;
    const float4* W4  = (const float4*)W0;
    float4 a0 = Ar4[tid],       a1 = Ar4[256 + tid];
    float4 a2 = Ar4[512 + tid], a3 = Ar4[768 + tid];
    float4 v0 = W4[tid],        v1 = W4[256 + tid];
    float4 v2 = W4[512 + tid],  v3 = W4[768 + tid];
    acc = a0.x * v0.x + a0.y * v0.y + a0.z * v0.z + a0.w * v0.w
        + a1.x * v1.x + a1.y * v1.y + a1.z * v1.z + a1.w * v1.w
        + a2.x * v2.x + a2.y * v2.y + a2.z * v2.z + a2.w * v2.w
        + a3.x * v3.x + a3.y * v3.y + a3.z * v3.z + a3.w * v3.w;
#endif
    if (tid < 64) acc += Ar[4096 + tid] * b0[tid];
    acc = wred_sum(acc);
    if (lane == 0) smem[wv] = acc;
    __syncthreads();
    if (tid == 0)
      gh0[r] = smem[0] + smem[1] + smem[2] + smem[3] + bhh0[r];
  }
}

// standalone summarize (layer 2)
__global__ __launch_bounds__(256) void k_sum(
    const float* __restrict__ h, const float* __restrict__ p,
    float* __restrict__ Zt) {
  __shared__ float yv[512];
  __shared__ int   si[64];
  __shared__ float st[64];
  sum_body(h, p, Zt, blockIdx.x, yv, si, st);
}

// ------------------------------------------------------------
// k_big: [0,780) split-bf16 MFMA GEMM — register-prefetch pipelined:
//          loads for tile ks+1 issue right after barrier-1, covering
//          the MFMA + barrier-2 + next pack/write window.
//        [780,1036) scatter normalized adjacency into A (ILP x4)
// ------------------------------------------------------------
__global__ __launch_bounds__(256) void k_big(
    const float* __restrict__ Wih0, const float* __restrict__ Zt,
    float* __restrict__ Cpart,
    const int* __restrict__ ei, const float* __restrict__ ew,
    const float* __restrict__ dinv, float* __restrict__ A) {
  __shared__ uint4 AsH[4][64];
  __shared__ uint4 AsL[4][64];
  __shared__ uint4 BsH[4][64];
  __shared__ uint4 BsL[4][64];
  const int bid = blockIdx.x, tid = threadIdx.x;
  if (bid < 780) {
    const int kc = bid & 3, row0 = (bid >> 2) * 64;
    const int wv = tid >> 6, ln = tid & 63;
    const int ar = tid >> 2, ak = tid & 3;        // A staging: row, kgroup
    const int bc = tid & 63, bk = tid >> 6;       // B staging: col, kgroup
    const int fr = ln & 15, fg = ln >> 4;         // frag row/col, kgroup
    f32x4 acc[4] = {{0.f,0.f,0.f,0.f},{0.f,0.f,0.f,0.f},
                    {0.f,0.f,0.f,0.f},{0.f,0.f,0.f,0.f}};
    const float* Arow = Wih0 + (size_t)(row0 + ar) * GINK + kc * 1024 + ak * 8;
    const float* Bcol = Zt + (size_t)(kc * 1024 + bk * 8) * NB + bc;
    // prologue: tile 0 into registers
    float4 ca0 = *(const float4*)(Arow);
    float4 ca1 = *(const float4*)(Arow + 4);
    float cq0 = Bcol[0 * NB], cq1 = Bcol[1 * NB];
    float cq2 = Bcol[2 * NB], cq3 = Bcol[3 * NB];
    float cq4 = Bcol[4 * NB], cq5 = Bcol[5 * NB];
    float cq6 = Bcol[6 * NB], cq7 = Bcol[7 * NB];
    for (int ks = 0; ks < 32; ++ks) {
      uint4 ah, al, bh, bl;
      split2(ca0.x, ca0.y, ah.x, al.x);
      split2(ca0.z, ca0.w, ah.y, al.y);
      split2(ca1.x, ca1.y, ah.z, al.z);
      split2(ca1.z, ca1.w, ah.w, al.w);
      split2(cq0, cq1, bh.x, bl.x);
      split2(cq2, cq3, bh.y, bl.y);
      split2(cq4, cq5, bh.z, bl.z);
      split2(cq6, cq7, bh.w, bl.w);
      AsH[ak][ar] = ah; AsL[ak][ar] = al;
      BsH[bk][bc] = bh; BsL[bk][bc] = bl;
      __syncthreads();
      // prefetch tile ks+1 (in flight across MFMA + barrier + next pack)
      if (ks < 31) {
        const float* An = Arow + (ks + 1) * 32;
        const float* bpn = Bcol + (size_t)(ks + 1) * 32 * NB;
        ca0 = *(const float4*)An;
        ca1 = *(const float4*)(An + 4);
        cq0 = bpn[0 * NB]; cq1 = bpn[1 * NB];
        cq2 = bpn[2 * NB]; cq3 = bpn[3 * NB];
        cq4 = bpn[4 * NB]; cq5 = bpn[5 * NB];
        cq6 = bpn[6 * NB]; cq7 = bpn[7 * NB];
      }
      bf16x8 afH = __builtin_bit_cast(bf16x8, AsH[fg][wv * 16 + fr]);
      bf16x8 afL = __builtin_bit_cast(bf16x8, AsL[fg][wv * 16 + fr]);
      #pragma unroll
      for (int nt = 0; nt < 4; ++nt) {
        bf16x8 bH = __builtin_bit_cast(bf16x8, BsH[fg][nt * 16 + fr]);
        bf16x8 bL = __builtin_bit_cast(bf16x8, BsL[fg][nt * 16 + fr]);
        acc[nt] = __builtin_amdgcn_mfma_f32_16x16x32_bf16(afH, bH, acc[nt], 0, 0, 0);
        acc[nt] = __builtin_amdgcn_mfma_f32_16x16x32_bf16(afH, bL, acc[nt], 0, 0, 0);
        acc[nt] = __builtin_amdgcn_mfma_f32_16x16x32_bf16(afL, bH, acc[nt], 0, 0, 0);
      }
      __syncthreads();
    }
    float* Cp = Cpart + (size_t)kc * M0 * NB + (size_t)row0 * NB;
    #pragma unroll
    for (int nt = 0; nt < 4; ++nt)
      #pragma unroll
      for (int j = 0; j < 4; ++j)
        Cp[(size_t)(wv * 16 + fg * 4 + j) * NB + nt * 16 + fr] = acc[nt][j];
  } else {
    const int g = bid - 780;
    const int s = g >> 2, sub = g & 3;
    const int* rowp = ei + (size_t)s * 2 * EE;
    const int* colp = rowp + EE;
    const float* ewp = ew + (size_t)s * EE;
    const float* dv = dinv + s * NN;
    float* Ab = A + (size_t)s * NN * NN;
    const int e0 = sub * 4096;
    for (int e = e0 + tid; e < e0 + 4096; e += 1024) {
      int r0 = rowp[e],       c0 = colp[e];
      int r1 = rowp[e + 256], c1 = colp[e + 256];
      int r2 = rowp[e + 512], c2 = colp[e + 512];
      int r3 = rowp[e + 768], c3 = colp[e + 768];
      float w0 = ewp[e],       w1 = ewp[e + 256];
      float w2 = ewp[e + 512], w3 = ewp[e + 768];
      atomicAdd(&Ab[(size_t)c0 * NN + r0], w0 * dv[r0] * dv[c0]);
      atomicAdd(&Ab[(size_t)c1 * NN + r1], w1 * dv[r1] * dv[c1]);
      atomicAdd(&Ab[(size_t)c2 * NN + r2], w2 * dv[r2] * dv[c2]);
      atomicAdd(&Ab[(size_t)c3 * NN + r3], w3 * dv[r3] * dv[c3]);
    }
    if (sub == 0) {
      atomicAdd(&Ab[(size_t)tid * NN + tid], dv[tid] * dv[tid]);
      atomicAdd(&Ab[(size_t)(tid + 256) * NN + tid + 256], dv[tid + 256] * dv[tid + 256]);
    }
  }
}

// ------------------------------------------------------------
// fp32 tile GEMM for the small layer: C[M][64] = A[M][4096] @ Bt
// ------------------------------------------------------------
__global__ __launch_bounds__(256) void k_gemm_f32(
    const float* __restrict__ A, const float* __restrict__ Bt,
    float* __restrict__ Cpart, int M, int kchunk) {
  const int row0 = blockIdx.x * 64;
  const int kc = blockIdx.y;
  const int tid = threadIdx.x;
  const int tx = tid & 15, ty = tid >> 4;
  __shared__ float As[16][68];
  __shared__ float Bs[16][64];
  float acc[4][4] = {};
  const int r_ld = tid >> 2, kq = (tid & 3) * 4;
  const int n_ld = tid & 63, kr = (tid >> 6) * 4;
  const int nks = kchunk >> 4;
  for (int kk = 0; kk < nks; ++kk) {
    const int kb = kc * kchunk + kk * 16;
    int row = row0 + r_ld;
    float4 a4 = make_float4(0.f, 0.f, 0.f, 0.f);
    if (row < M) a4 = *(const float4*)(A + (size_t)row * GINK + kb + kq);
    As[kq + 0][r_ld] = a4.x; As[kq + 1][r_ld] = a4.y;
    As[kq + 2][r_ld] = a4.z; As[kq + 3][r_ld] = a4.w;
    #pragma unroll
    for (int i = 0; i < 4; ++i)
      Bs[kr + i][n_ld] = Bt[(size_t)(kb + kr + i) * NB + n_ld];
    __syncthreads();
    #pragma unroll
    for (int k = 0; k < 16; ++k) {
      float4 a4v = *(const float4*)&As[k][ty * 4];
      float4 b4 = *(const float4*)&Bs[k][tx * 4];
      float a[4] = {a4v.x, a4v.y, a4v.z, a4v.w};
      float bb[4] = {b4.x, b4.y, b4.z, b4.w};
      #pragma unroll
      for (int i = 0; i < 4; ++i)
        #pragma unroll
        for (int j = 0; j < 4; ++j) acc[i][j] += a[i] * bb[j];
    }
    __syncthreads();
  }
  float* Cp = Cpart + (size_t)kc * M * NB;
  #pragma unroll
  for (int i = 0; i < 4; ++i) {
    int row = row0 + ty * 4 + i;
    if (row < M)
      *(float4*)(Cp + (size_t)row * NB + tx * 4) =
          make_float4(acc[i][0], acc[i][1], acc[i][2], acc[i][3]);
  }
}

// ------------------------------------------------------------
// GRU nonlinearity, layer 0 (4 K-partials)
// ------------------------------------------------------------
__global__ __launch_bounds__(256) void k_gru0(
    const float* __restrict__ P, const float* __restrict__ gh,
    const float* __restrict__ bih,
    const float* __restrict__ W0, const float* __restrict__ b0,
    float* __restrict__ hn) {
  const int e = blockIdx.x * 256 + threadIdx.x;
  const int j = e >> 6, b = e & 63;
  const size_t M64 = (size_t)M0 * NB;
  float ir = bih[j], iz = bih[H0S + j], in_ = bih[2 * H0S + j];
  #pragma unroll
  for (int kc = 0; kc < 4; ++kc) {
    const float* Pc = P + kc * M64;
    ir  += Pc[(size_t)j * NB + b];
    iz  += Pc[(size_t)(H0S + j) * NB + b];
    in_ += Pc[(size_t)(2 * H0S + j) * NB + b];
  }
  float r = sigm(ir + gh[j]);
  float z = sigm(iz + gh[H0S + j]);
  float n = tanhf(in_ + r * gh[2 * H0S + j]);
  float hv = (j < 4096) ? W0[j] : b0[j - 4096];
  hn[(size_t)b * H0S + j] = (1.f - z) * n + z * hv;
}

// ------------------------------------------------------------
// xw0[b] = x[b] @ Wn(b)^T   (512x64 @ 64x64)
// ------------------------------------------------------------
__global__ __launch_bounds__(256) void k_xw(
    const float* __restrict__ x, const float* __restrict__ hn0,
    float* __restrict__ xw) {
  const int b = blockIdx.y, n0 = blockIdx.x * 64;
  const int tid = threadIdx.x;
  const int tx = tid & 15, ty = tid >> 4;
  __shared__ float As[64][68];
  __shared__ float Bs[64][68];
  const float* xb = x + (size_t)b * NN * FIN + (size_t)n0 * FIN;
  const float* wb = hn0 + (size_t)b * H0S;
  for (int id = tid; id < 1024; id += 256) {
    int m = id >> 4, kq = (id & 15) * 4;
    float4 v = *(const float4*)(xb + m * FIN + kq);
    As[kq + 0][m] = v.x; As[kq + 1][m] = v.y; As[kq + 2][m] = v.z; As[kq + 3][m] = v.w;
    float4 w = *(const float4*)(wb + m * FIN + kq);
    Bs[kq + 0][m] = w.x; Bs[kq + 1][m] = w.y; Bs[kq + 2][m] = w.z; Bs[kq + 3][m] = w.w;
  }
  __syncthreads();
  float acc[4][4] = {};
  for (int k = 0; k < 64; ++k) {
    float4 a4 = *(const float4*)&As[k][ty * 4];
    float4 b4 = *(const float4*)&Bs[k][tx * 4];
    float a[4] = {a4.x, a4.y, a4.z, a4.w};
    float bb[4] = {b4.x, b4.y, b4.z, b4.w};
    #pragma unroll
    for (int i = 0; i < 4; ++i)
      #pragma unroll
      for (int j = 0; j < 4; ++j) acc[i][j] += a[i] * bb[j];
  }
  #pragma unroll
  for (int i = 0; i < 4; ++i)
    *(float4*)(xw + (size_t)b * NN * FIN + (size_t)(n0 + ty * 4 + i) * FIN + tx * 4) =
        make_float4(acc[i][0], acc[i][1], acc[i][2], acc[i][3]);
}

// ------------------------------------------------------------
// h1 = relu(LN(A @ xw + bn))
// ------------------------------------------------------------
__global__ __launch_bounds__(256) void k_gcnmm(
    const float* __restrict__ Adj, const float* __restrict__ xw,
    const float* __restrict__ hn0,
    const float* __restrict__ gam, const float* __restrict__ bet,
    float* __restrict__ h1) {
  const int b = blockIdx.y, n0 = blockIdx.x * 64;
  const int tid = threadIdx.x;
  const int tx = tid & 15, ty = tid >> 4;
  __shared__ float As[16][68];
  __shared__ float Bs[16][64];
  __shared__ float Ct[64][68];
  __shared__ float sbn[64], sg[64], sbt[64];
  if (tid < 64) {
    sbn[tid] = hn0[(size_t)b * H0S + 4096 + tid];
    sg[tid] = gam[tid]; sbt[tid] = bet[tid];
  }
  const float* Ab = Adj + (size_t)b * NN * NN;
  const float* xb = xw + (size_t)b * NN * FIN;
  float acc[4][4] = {};
  const int r_ld = tid >> 2, kq = (tid & 3) * 4;
  const int n_ld = tid & 63, kr = (tid >> 6) * 4;
  for (int kk = 0; kk < 32; ++kk) {
    const int kb = kk * 16;
    float4 a4 = *(const float4*)(Ab + (size_t)(n0 + r_ld) * NN + kb + kq);
    As[kq + 0][r_ld] = a4.x; As[kq + 1][r_ld] = a4.y;
    As[kq + 2][r_ld] = a4.z; As[kq + 3][r_ld] = a4.w;
    #pragma unroll
    for (int i = 0; i < 4; ++i)
      Bs[kr + i][n_ld] = xb[(size_t)(kb + kr + i) * FIN + n_ld];
    __syncthreads();
    #pragma unroll
    for (int k = 0; k < 16; ++k) {
      float4 a4v = *(const float4*)&As[k][ty * 4];
      float4 b4 = *(const float4*)&Bs[k][tx * 4];
      float a[4] = {a4v.x, a4v.y, a4v.z, a4v.w};
      float bb[4] = {b4.x, b4.y, b4.z, b4.w};
      #pragma unroll
      for (int i = 0; i < 4; ++i)
        #pragma unroll
        for (int j = 0; j < 4; ++j) acc[i][j] += a[i] * bb[j];
    }
    __syncthreads();
  }
  #pragma unroll
  for (int i = 0; i < 4; ++i)
    *(float4*)&Ct[ty * 4 + i][tx * 4] =
        make_float4(acc[i][0], acc[i][1], acc[i][2], acc[i][3]);
  __syncthreads();
  const int lane = tid & 63, wid = tid >> 6;
  for (int m = wid; m < 64; m += 4) {
    float v = Ct[m][lane] + sbn[lane];
    float s1 = wall_sum(v);
    float s2 = wall_sum(v * v);
    float mu = s1 * (1.f / 64.f);
    float var = s2 * (1.f / 64.f) - mu * mu;
    float o = (v - mu) * rsqrtf(var + 1e-5f) * sg[lane] + sbt[lane];
    h1[(size_t)b * NN * FIN + (size_t)(n0 + m) * FIN + lane] = fmaxf(o, 0.f);
  }
}

// ------------------------------------------------------------
// out = A @ (h1 @ Wn1^T) + bn1 ; gru1 fused (redundant per block)
// ------------------------------------------------------------
__global__ __launch_bounds__(256) void k_gcnout(
    const float* __restrict__ Adj, const float* __restrict__ h1,
    const float* __restrict__ P1, const float* __restrict__ gh1,
    const float* __restrict__ bih1,
    const float* __restrict__ W1, const float* __restrict__ b1,
    float* __restrict__ out) {
  const int s = blockIdx.x >> 2, q = blockIdx.x & 3;
  const int tid = threadIdx.x;
  const int ln = tid & 63, wv = tid >> 6;
  __shared__ float w0s[64], w1s[64], bns[2];
  __shared__ float xwl[NN * 2];
  if (tid < H1S) {
    const int j = tid;
    float ir = bih1[j], iz = bih1[H1S + j], in_ = bih1[2 * H1S + j];
    #pragma unroll
    for (int kc = 0; kc < 16; ++kc) {
      const float* Pc = P1 + kc * (M1 * NB);
      ir  += Pc[j * NB + s];
      iz  += Pc[(H1S + j) * NB + s];
      in_ += Pc[(2 * H1S + j) * NB + s];
    }
    float r = sigm(ir + gh1[j]);
    float z = sigm(iz + gh1[H1S + j]);
    float n = tanhf(in_ + r * gh1[2 * H1S + j]);
    float hv = (j < 128) ? W1[j] : b1[j - 128];
    float hnv = (1.f - z) * n + z * hv;
    if (j < 64) w0s[j] = hnv;
    else if (j < 128) w1s[j - 64] = hnv;
    else bns[j - 128] = hnv;
  }
  __syncthreads();
  const float* h1b = h1 + (size_t)s * NN * FIN;
  for (int n = wv * 128; n < wv * 128 + 128; ++n) {
    float v = h1b[n * FIN + ln];
    float s0 = wred_sum(v * w0s[ln]);
    float s1 = wred_sum(v * w1s[ln]);
    if (ln == 0) { xwl[n * 2] = s0; xwl[n * 2 + 1] = s1; }
  }
  __syncthreads();
  const float* Ab = Adj + (size_t)s * NN * NN;
  for (int i = 0; i < 32; ++i) {
    int c = q * 128 + wv * 32 + i;
    const float* Ar = Ab + (size_t)c * NN;
    float a0 = 0.f, a1 = 0.f;
    #pragma unroll
    for (int j = 0; j < 8; ++j) {
      int r = ln + j * 64;
      float av = Ar[r];
      a0 += av * xwl[r * 2]; a1 += av * xwl[r * 2 + 1];
    }
    a0 = wred_sum(a0); a1 = wred_sum(a1);
    if (ln == 0) {
      out[(size_t)s * NN * 2 + c * 2]     = a0 + bns[0];
      out[(size_t)s * NN * 2 + c * 2 + 1] = a1 + bns[1];
    }
  }
}

// ============================================================
extern "C" void kernel_launch(void* const* d_in, const int* in_sizes, int n_in,
                              void* d_out, int out_size, void* d_ws, size_t ws_size,
                              hipStream_t stream) {
  const float* x    = (const float*)d_in[0];
  const int*   ei   = (const int*)  d_in[1];
  const float* ew   = (const float*)d_in[2];
  const float* p0   = (const float*)d_in[3];
  const float* p1   = (const float*)d_in[4];
  const float* W0   = (const float*)d_in[5];
  const float* b0   = (const float*)d_in[6];
  const float* W1   = (const float*)d_in[7];
  const float* b1   = (const float*)d_in[8];
  const float* lng  = (const float*)d_in[9];
  const float* lnb  = (const float*)d_in[10];
  const float* Wih0 = (const float*)d_in[11];
  const float* Whh0 = (const float*)d_in[12];
  const float* bih0 = (const float*)d_in[13];
  const float* bhh0 = (const float*)d_in[14];
  const float* Wih1 = (const float*)d_in[15];
  const float* Whh1 = (const float*)d_in[16];
  const float* bih1 = (const float*)d_in[17];
  const float* bhh1 = (const float*)d_in[18];

  float* ws = (float*)d_ws;
  float* P0   = ws + 0;          // 4*12480*64 = 3,194,880 (P1: 16*390*64)
  float* P1   = ws + 0;
  float* gh0  = ws + 3194880;    // 12,480
  float* gh1  = ws + 3207360;    // 448
  float* Zt0  = ws + 3207808;    // 262,144
  float* Zt1  = ws + 3207808;
  float* hn0  = ws + 3469952;    // 266,240
  float* xw0  = ws + 3744512;    // 2,097,152
  float* h1   = ws + 5841664;    // 2,097,152
  float* dinv = ws + 7938816;    // 32,768
  float* A    = ws + 7971584;    // 16,777,216 (end 24,748,800 floats = 99.0 MB)
  float* out  = (float*)d_out;

  k_misc  <<<13218, 256, 0, stream>>>(Whh1, bhh1, W1, b1, ei, ew, x, p0,
                                      gh1, A, dinv, Zt0,
                                      Whh0, bhh0, W0, b0, gh0);
  k_big   <<<1036, 256, 0, stream>>>(Wih0, Zt0, P0, ei, ew, dinv, A);
  k_gru0  <<<1040, 256, 0, stream>>>(P0, gh0, bih0, W0, b0, hn0);
  k_xw    <<<dim3(8, 64), 256, 0, stream>>>(x, hn0, xw0);
  k_gcnmm <<<dim3(8, 64), 256, 0, stream>>>(A, xw0, hn0, lng, lnb, h1);
  k_sum   <<<64, 256, 0, stream>>>(h1, p1, Zt1);
  k_gemm_f32<<<dim3(7, 16), 256, 0, stream>>>(Wih1, Zt1, P1, M1, 256);
  k_gcnout<<<256, 256, 0, stream>>>(A, h1, P1, gh1, bih1, W1, b1, out);
}

// Round 19
// 431.635 us; speedup vs baseline: 1.0324x; 1.0324x over previous
//
#include <hip/hip_runtime.h>
#include <math.h>

// ---- problem constants ----
#define NB   64      // batch / scenarios
#define NN   512     // nodes
#define FIN  64      // feature dim (IN == HID)
#define EE   16384   // edges per scenario
#define H0S  4160    // HID*IN + HID
#define H1S  130     // OUT*HID + OUT
#define M0   12480   // 3*H0S
#define M1   390     // 3*H1S
#define GINK 4096    // TOPK*IN

typedef __attribute__((ext_vector_type(8))) short bf16x8;
typedef __attribute__((ext_vector_type(4))) float f32x4;

__device__ __forceinline__ float wred_sum(float v) {
  #pragma unroll
  for (int off = 32; off; off >>= 1) v += __shfl_down(v, off);
  return v;
}
__device__ __forceinline__ float wall_sum(float v) {
  #pragma unroll
  for (int off = 32; off; off >>= 1) v += __shfl_xor(v, off);
  return v;
}
__device__ __forceinline__ float sigm(float x) { return 1.f / (1.f + expf(-x)); }
__device__ __forceinline__ unsigned short f2bfu(float f) {
  unsigned int u = __float_as_uint(f);
  return (unsigned short)((u + 0x7fffu + ((u >> 16) & 1u)) >> 16);
}
// split a,b into packed hi bf16 pair and lo (residual) bf16 pair
__device__ __forceinline__ void split2(float a, float b,
                                       unsigned int& hi, unsigned int& lo) {
  unsigned short ha = f2bfu(a), hb = f2bfu(b);
  float ra = a - __uint_as_float((unsigned int)ha << 16);
  float rb = b - __uint_as_float((unsigned int)hb << 16);
  hi = (unsigned int)ha | ((unsigned int)hb << 16);
  lo = (unsigned int)f2bfu(ra) | ((unsigned int)f2bfu(rb) << 16);
}

#if __has_builtin(__builtin_amdgcn_global_load_lds)
#define HAVE_GLL 1
__device__ __forceinline__ void gload_lds16(const void* g, void* l) {
  __builtin_amdgcn_global_load_lds(
      (const __attribute__((address_space(1))) unsigned int*)g,
      (__attribute__((address_space(3))) unsigned int*)l, 16, 0, 0);
}
#else
#define HAVE_GLL 0
#endif

// ------------------------------------------------------------
// summarize body (r16-exact)
// ------------------------------------------------------------
__device__ __forceinline__ void sum_body(
    const float* __restrict__ h, const float* __restrict__ p,
    float* __restrict__ Zt, int b,
    float* yv, int* si, float* st) {
  const int tid = threadIdx.x;
  const int ln = tid & 63, wv = tid >> 6;
  float pv = p[ln];
  float s = wall_sum(pv * pv);
  float pn = pv / (sqrtf(s) + 1e-8f);
  const float* hb = h + (size_t)b * NN * FIN;
  for (int n0 = wv * 128; n0 < wv * 128 + 128; n0 += 4) {
    float a0 = hb[(n0 + 0) * FIN + ln] * pn;
    float a1 = hb[(n0 + 1) * FIN + ln] * pn;
    float a2 = hb[(n0 + 2) * FIN + ln] * pn;
    float a3 = hb[(n0 + 3) * FIN + ln] * pn;
    a0 = wred_sum(a0); a1 = wred_sum(a1);
    a2 = wred_sum(a2); a3 = wred_sum(a3);
    if (ln == 0) {
      yv[n0] = a0; yv[n0 + 1] = a1; yv[n0 + 2] = a2; yv[n0 + 3] = a3;
    }
  }
  __syncthreads();
  if (wv == 0) {
    float rv[8];
    #pragma unroll
    for (int j = 0; j < 8; ++j) rv[j] = yv[j * 64 + ln];
    for (int t = 0; t < 64; ++t) {
      float bv = rv[0]; int bj = 0;
      #pragma unroll
      for (int j = 1; j < 8; ++j) if (rv[j] > bv) { bv = rv[j]; bj = j; }
      int bn = bj * 64 + ln;
      #pragma unroll
      for (int off = 1; off < 64; off <<= 1) {
        float ov = __shfl_xor(bv, off); int on = __shfl_xor(bn, off);
        if (ov > bv || (ov == bv && on < bn)) { bv = ov; bn = on; }
      }
      if (ln == 0) { si[t] = bn; st[t] = tanhf(bv); }
      #pragma unroll
      for (int j = 0; j < 8; ++j) if (bn == j * 64 + ln) rv[j] = -3.4e38f;
    }
  }
  __syncthreads();
  for (int t = wv * 16; t < wv * 16 + 16; ++t) {
    int n = si[t]; float sc = st[t];
    Zt[(size_t)(t * 64 + ln) * NB + b] = hb[n * FIN + ln] * sc;
  }
}

// ------------------------------------------------------------
// k_misc (r16-exact): deg/dinv | summarize0 | zero A | gh1 | gh0 gll
// ------------------------------------------------------------
__global__ __launch_bounds__(256) void k_misc(
    const float* __restrict__ Whh1, const float* __restrict__ bhh1,
    const float* __restrict__ W1,   const float* __restrict__ b1,
    const int* __restrict__ ei, const float* __restrict__ ew,
    const float* __restrict__ x, const float* __restrict__ p0,
    float* __restrict__ gh1, float* __restrict__ A,
    float* __restrict__ dinv, float* __restrict__ Zt0,
    const float* __restrict__ Whh0, const float* __restrict__ bhh0,
    const float* __restrict__ W0,   const float* __restrict__ b0,
    float* __restrict__ gh0) {
  __shared__ float rowb[4096];
  __shared__ float smem[512];
  __shared__ int   ssel[64];
  __shared__ float sst[64];
  const int bid = blockIdx.x, tid = threadIdx.x;
  const int lane = tid & 63, wv = tid >> 6;
  if (bid < 64) {
    const int b = bid;
    smem[tid] = 1.0f; smem[tid + 256] = 1.0f;
    __syncthreads();
    const int* colp = ei + (size_t)b * 2 * EE + EE;
    const float* ewp = ew + (size_t)b * EE;
    for (int e = tid; e < EE; e += 1024) {
      int   c0 = colp[e],       c1 = colp[e + 256];
      int   c2 = colp[e + 512], c3 = colp[e + 768];
      float w0 = ewp[e],        w1 = ewp[e + 256];
      float w2 = ewp[e + 512],  w3 = ewp[e + 768];
      atomicAdd(&smem[c0], w0); atomicAdd(&smem[c1], w1);
      atomicAdd(&smem[c2], w2); atomicAdd(&smem[c3], w3);
    }
    __syncthreads();
    dinv[b * NN + tid]       = rsqrtf(smem[tid]);
    dinv[b * NN + tid + 256] = rsqrtf(smem[tid + 256]);
  } else if (bid < 128) {
    sum_body(x, p0, Zt0, bid - 64, smem, ssel, sst);
  } else if (bid < 640) {
    float4* Az = (float4*)A + (size_t)(bid - 128) * 8192;
    #pragma unroll 8
    for (int i = 0; i < 32; ++i) Az[i * 256 + tid] = make_float4(0.f, 0.f, 0.f, 0.f);
  } else if (bid < 738) {
    const int r = (bid - 640) * 4 + wv;
    if (r < M1) {
      const float* Ar = Whh1 + (size_t)r * H1S;
      float acc = Ar[lane] * W1[lane] + Ar[64 + lane] * W1[64 + lane];
      if (lane < 2) acc += Ar[128 + lane] * b1[lane];
      acc = wred_sum(acc);
      if (lane == 0) gh1[r] = acc + bhh1[r];
    }
  } else {
    const int r = bid - 738;
    const float* Ar = Whh0 + (size_t)r * H0S;
    float acc;
#if HAVE_GLL
    #pragma unroll
    for (int i = 0; i < 4; ++i) {
      const int c = (i * 4 + wv) * 64;
      gload_lds16((const uint4*)Ar + c + lane, (uint4*)rowb + c);
    }
    __syncthreads();
    const float4* R4 = (const float4*)rowb;
    const float4* W4 = (const float4*)W0;
    float4 a0 = R4[tid],       a1 = R4[256 + tid];
    float4 a2 = R4[512 + tid], a3 = R4[768 + tid];
    float4 v0 = W4[tid],       v1 = W4[256 + tid];
    float4 v2 = W4[512 + tid], v3 = W4[768 + tid];
    acc = a0.x * v0.x + a0.y * v0.y + a0.z * v0.z + a0.w * v0.w
        + a1.x * v1.x + a1.y * v1.y + a1.z * v1.z + a1.w * v1.w
        + a2.x * v2.x + a2.y * v2.y + a2.z * v2.z + a2.w * v2.w
        + a3.x * v3.x + a3.y * v3.y + a3.z * v3.z + a3.w * v3.w;
#else
    const float4* Ar4 = (const float4*)Ar;
    const float4* W4  = (const float4*)W0;
    float4 a0 = Ar4[tid],       a1 = Ar4[256 + tid];
    float4 a2 = Ar4[512 + tid], a3 = Ar4[768 + tid];
    float4 v0 = W4[tid],        v1 = W4[256 + tid];
    float4 v2 = W4[512 + tid],  v3 = W4[768 + tid];
    acc = a0.x * v0.x + a0.y * v0.y + a0.z * v0.z + a0.w * v0.w
        + a1.x * v1.x + a1.y * v1.y + a1.z * v1.z + a1.w * v1.w
        + a2.x * v2.x + a2.y * v2.y + a2.z * v2.z + a2.w * v2.w
        + a3.x * v3.x + a3.y * v3.y + a3.z * v3.z + a3.w * v3.w;
#endif
    if (tid < 64) acc += Ar[4096 + tid] * b0[tid];
    acc = wred_sum(acc);
    if (lane == 0) smem[wv] = acc;
    __syncthreads();
    if (tid == 0)
      gh0[r] = smem[0] + smem[1] + smem[2] + smem[3] + bhh0[r];
  }
}

// standalone summarize (layer 2)
__global__ __launch_bounds__(256) void k_sum(
    const float* __restrict__ h, const float* __restrict__ p,
    float* __restrict__ Zt) {
  __shared__ float yv[512];
  __shared__ int   si[64];
  __shared__ float st[64];
  sum_body(h, p, Zt, blockIdx.x, yv, si, st);
}

// ------------------------------------------------------------
// k_big (r16-exact): split-bf16 MFMA GEMM + scatter
// ------------------------------------------------------------
__global__ __launch_bounds__(256) void k_big(
    const float* __restrict__ Wih0, const float* __restrict__ Zt,
    float* __restrict__ Cpart,
    const int* __restrict__ ei, const float* __restrict__ ew,
    const float* __restrict__ dinv, float* __restrict__ A) {
  __shared__ uint4 AsH[4][64];
  __shared__ uint4 AsL[4][64];
  __shared__ uint4 BsH[4][64];
  __shared__ uint4 BsL[4][64];
  const int bid = blockIdx.x, tid = threadIdx.x;
  if (bid < 780) {
    const int kc = bid & 3, row0 = (bid >> 2) * 64;
    const int wv = tid >> 6, ln = tid & 63;
    const int ar = tid >> 2, ak = tid & 3;
    const int bc = tid & 63, bk = tid >> 6;
    const int fr = ln & 15, fg = ln >> 4;
    f32x4 acc[4] = {{0.f,0.f,0.f,0.f},{0.f,0.f,0.f,0.f},
                    {0.f,0.f,0.f,0.f},{0.f,0.f,0.f,0.f}};
    const float* Arow = Wih0 + (size_t)(row0 + ar) * GINK + kc * 1024 + ak * 8;
    const float* Bcol = Zt + (size_t)(kc * 1024 + bk * 8) * NB + bc;
    for (int ks = 0; ks < 32; ++ks) {
      float4 a0 = *(const float4*)(Arow + ks * 32);
      float4 a1 = *(const float4*)(Arow + ks * 32 + 4);
      const float* bp = Bcol + (size_t)ks * 32 * NB;
      float q0 = bp[0 * NB], q1 = bp[1 * NB], q2 = bp[2 * NB], q3 = bp[3 * NB];
      float q4 = bp[4 * NB], q5 = bp[5 * NB], q6 = bp[6 * NB], q7 = bp[7 * NB];
      uint4 ah, al, bh, bl;
      split2(a0.x, a0.y, ah.x, al.x);
      split2(a0.z, a0.w, ah.y, al.y);
      split2(a1.x, a1.y, ah.z, al.z);
      split2(a1.z, a1.w, ah.w, al.w);
      split2(q0, q1, bh.x, bl.x);
      split2(q2, q3, bh.y, bl.y);
      split2(q4, q5, bh.z, bl.z);
      split2(q6, q7, bh.w, bl.w);
      AsH[ak][ar] = ah; AsL[ak][ar] = al;
      BsH[bk][bc] = bh; BsL[bk][bc] = bl;
      __syncthreads();
      bf16x8 afH = __builtin_bit_cast(bf16x8, AsH[fg][wv * 16 + fr]);
      bf16x8 afL = __builtin_bit_cast(bf16x8, AsL[fg][wv * 16 + fr]);
      #pragma unroll
      for (int nt = 0; nt < 4; ++nt) {
        bf16x8 bH = __builtin_bit_cast(bf16x8, BsH[fg][nt * 16 + fr]);
        bf16x8 bL = __builtin_bit_cast(bf16x8, BsL[fg][nt * 16 + fr]);
        acc[nt] = __builtin_amdgcn_mfma_f32_16x16x32_bf16(afH, bH, acc[nt], 0, 0, 0);
        acc[nt] = __builtin_amdgcn_mfma_f32_16x16x32_bf16(afH, bL, acc[nt], 0, 0, 0);
        acc[nt] = __builtin_amdgcn_mfma_f32_16x16x32_bf16(afL, bH, acc[nt], 0, 0, 0);
      }
      __syncthreads();
    }
    float* Cp = Cpart + (size_t)kc * M0 * NB + (size_t)row0 * NB;
    #pragma unroll
    for (int nt = 0; nt < 4; ++nt)
      #pragma unroll
      for (int j = 0; j < 4; ++j)
        Cp[(size_t)(wv * 16 + fg * 4 + j) * NB + nt * 16 + fr] = acc[nt][j];
  } else {
    const int g = bid - 780;
    const int s = g >> 2, sub = g & 3;
    const int* rowp = ei + (size_t)s * 2 * EE;
    const int* colp = rowp + EE;
    const float* ewp = ew + (size_t)s * EE;
    const float* dv = dinv + s * NN;
    float* Ab = A + (size_t)s * NN * NN;
    const int e0 = sub * 4096;
    for (int e = e0 + tid; e < e0 + 4096; e += 1024) {
      int r0 = rowp[e],       c0 = colp[e];
      int r1 = rowp[e + 256], c1 = colp[e + 256];
      int r2 = rowp[e + 512], c2 = colp[e + 512];
      int r3 = rowp[e + 768], c3 = colp[e + 768];
      float w0 = ewp[e],       w1 = ewp[e + 256];
      float w2 = ewp[e + 512], w3 = ewp[e + 768];
      atomicAdd(&Ab[(size_t)c0 * NN + r0], w0 * dv[r0] * dv[c0]);
      atomicAdd(&Ab[(size_t)c1 * NN + r1], w1 * dv[r1] * dv[c1]);
      atomicAdd(&Ab[(size_t)c2 * NN + r2], w2 * dv[r2] * dv[c2]);
      atomicAdd(&Ab[(size_t)c3 * NN + r3], w3 * dv[r3] * dv[c3]);
    }
    if (sub == 0) {
      atomicAdd(&Ab[(size_t)tid * NN + tid], dv[tid] * dv[tid]);
      atomicAdd(&Ab[(size_t)(tid + 256) * NN + tid + 256], dv[tid + 256] * dv[tid + 256]);
    }
  }
}

// ------------------------------------------------------------
// fp32 tile GEMM for the small layer (r16-exact)
// ------------------------------------------------------------
__global__ __launch_bounds__(256) void k_gemm_f32(
    const float* __restrict__ A, const float* __restrict__ Bt,
    float* __restrict__ Cpart, int M, int kchunk) {
  const int row0 = blockIdx.x * 64;
  const int kc = blockIdx.y;
  const int tid = threadIdx.x;
  const int tx = tid & 15, ty = tid >> 4;
  __shared__ float As[16][68];
  __shared__ float Bs[16][64];
  float acc[4][4] = {};
  const int r_ld = tid >> 2, kq = (tid & 3) * 4;
  const int n_ld = tid & 63, kr = (tid >> 6) * 4;
  const int nks = kchunk >> 4;
  for (int kk = 0; kk < nks; ++kk) {
    const int kb = kc * kchunk + kk * 16;
    int row = row0 + r_ld;
    float4 a4 = make_float4(0.f, 0.f, 0.f, 0.f);
    if (row < M) a4 = *(const float4*)(A + (size_t)row * GINK + kb + kq);
    As[kq + 0][r_ld] = a4.x; As[kq + 1][r_ld] = a4.y;
    As[kq + 2][r_ld] = a4.z; As[kq + 3][r_ld] = a4.w;
    #pragma unroll
    for (int i = 0; i < 4; ++i)
      Bs[kr + i][n_ld] = Bt[(size_t)(kb + kr + i) * NB + n_ld];
    __syncthreads();
    #pragma unroll
    for (int k = 0; k < 16; ++k) {
      float4 a4v = *(const float4*)&As[k][ty * 4];
      float4 b4 = *(const float4*)&Bs[k][tx * 4];
      float a[4] = {a4v.x, a4v.y, a4v.z, a4v.w};
      float bb[4] = {b4.x, b4.y, b4.z, b4.w};
      #pragma unroll
      for (int i = 0; i < 4; ++i)
        #pragma unroll
        for (int j = 0; j < 4; ++j) acc[i][j] += a[i] * bb[j];
    }
    __syncthreads();
  }
  float* Cp = Cpart + (size_t)kc * M * NB;
  #pragma unroll
  for (int i = 0; i < 4; ++i) {
    int row = row0 + ty * 4 + i;
    if (row < M)
      *(float4*)(Cp + (size_t)row * NB + tx * 4) =
          make_float4(acc[i][0], acc[i][1], acc[i][2], acc[i][3]);
  }
}

// ------------------------------------------------------------
// GRU nonlinearity, layer 0 (r16-exact)
// ------------------------------------------------------------
__global__ __launch_bounds__(256) void k_gru0(
    const float* __restrict__ P, const float* __restrict__ gh,
    const float* __restrict__ bih,
    const float* __restrict__ W0, const float* __restrict__ b0,
    float* __restrict__ hn) {
  const int e = blockIdx.x * 256 + threadIdx.x;
  const int j = e >> 6, b = e & 63;
  const size_t M64 = (size_t)M0 * NB;
  float ir = bih[j], iz = bih[H0S + j], in_ = bih[2 * H0S + j];
  #pragma unroll
  for (int kc = 0; kc < 4; ++kc) {
    const float* Pc = P + kc * M64;
    ir  += Pc[(size_t)j * NB + b];
    iz  += Pc[(size_t)(H0S + j) * NB + b];
    in_ += Pc[(size_t)(2 * H0S + j) * NB + b];
  }
  float r = sigm(ir + gh[j]);
  float z = sigm(iz + gh[H0S + j]);
  float n = tanhf(in_ + r * gh[2 * H0S + j]);
  float hv = (j < 4096) ? W0[j] : b0[j - 4096];
  hn[(size_t)b * H0S + j] = (1.f - z) * n + z * hv;
}

// ------------------------------------------------------------
// xw0[b] = x[b] @ Wn(b)^T (r16-exact)
// ------------------------------------------------------------
__global__ __launch_bounds__(256) void k_xw(
    const float* __restrict__ x, const float* __restrict__ hn0,
    float* __restrict__ xw) {
  const int b = blockIdx.y, n0 = blockIdx.x * 64;
  const int tid = threadIdx.x;
  const int tx = tid & 15, ty = tid >> 4;
  __shared__ float As[64][68];
  __shared__ float Bs[64][68];
  const float* xb = x + (size_t)b * NN * FIN + (size_t)n0 * FIN;
  const float* wb = hn0 + (size_t)b * H0S;
  for (int id = tid; id < 1024; id += 256) {
    int m = id >> 4, kq = (id & 15) * 4;
    float4 v = *(const float4*)(xb + m * FIN + kq);
    As[kq + 0][m] = v.x; As[kq + 1][m] = v.y; As[kq + 2][m] = v.z; As[kq + 3][m] = v.w;
    float4 w = *(const float4*)(wb + m * FIN + kq);
    Bs[kq + 0][m] = w.x; Bs[kq + 1][m] = w.y; Bs[kq + 2][m] = w.z; Bs[kq + 3][m] = w.w;
  }
  __syncthreads();
  float acc[4][4] = {};
  for (int k = 0; k < 64; ++k) {
    float4 a4 = *(const float4*)&As[k][ty * 4];
    float4 b4 = *(const float4*)&Bs[k][tx * 4];
    float a[4] = {a4.x, a4.y, a4.z, a4.w};
    float bb[4] = {b4.x, b4.y, b4.z, b4.w};
    #pragma unroll
    for (int i = 0; i < 4; ++i)
      #pragma unroll
      for (int j = 0; j < 4; ++j) acc[i][j] += a[i] * bb[j];
  }
  #pragma unroll
  for (int i = 0; i < 4; ++i)
    *(float4*)(xw + (size_t)b * NN * FIN + (size_t)(n0 + ty * 4 + i) * FIN + tx * 4) =
        make_float4(acc[i][0], acc[i][1], acc[i][2], acc[i][3]);
}

// ------------------------------------------------------------
// h1 = relu(LN(A @ xw + bn)) (r16-exact)
// ------------------------------------------------------------
__global__ __launch_bounds__(256) void k_gcnmm(
    const float* __restrict__ Adj, const float* __restrict__ xw,
    const float* __restrict__ hn0,
    const float* __restrict__ gam, const float* __restrict__ bet,
    float* __restrict__ h1) {
  const int b = blockIdx.y, n0 = blockIdx.x * 64;
  const int tid = threadIdx.x;
  const int tx = tid & 15, ty = tid >> 4;
  __shared__ float As[16][68];
  __shared__ float Bs[16][64];
  __shared__ float Ct[64][68];
  __shared__ float sbn[64], sg[64], sbt[64];
  if (tid < 64) {
    sbn[tid] = hn0[(size_t)b * H0S + 4096 + tid];
    sg[tid] = gam[tid]; sbt[tid] = bet[tid];
  }
  const float* Ab = Adj + (size_t)b * NN * NN;
  const float* xb = xw + (size_t)b * NN * FIN;
  float acc[4][4] = {};
  const int r_ld = tid >> 2, kq = (tid & 3) * 4;
  const int n_ld = tid & 63, kr = (tid >> 6) * 4;
  for (int kk = 0; kk < 32; ++kk) {
    const int kb = kk * 16;
    float4 a4 = *(const float4*)(Ab + (size_t)(n0 + r_ld) * NN + kb + kq);
    As[kq + 0][r_ld] = a4.x; As[kq + 1][r_ld] = a4.y;
    As[kq + 2][r_ld] = a4.z; As[kq + 3][r_ld] = a4.w;
    #pragma unroll
    for (int i = 0; i < 4; ++i)
      Bs[kr + i][n_ld] = xb[(size_t)(kb + kr + i) * FIN + n_ld];
    __syncthreads();
    #pragma unroll
    for (int k = 0; k < 16; ++k) {
      float4 a4v = *(const float4*)&As[k][ty * 4];
      float4 b4 = *(const float4*)&Bs[k][tx * 4];
      float a[4] = {a4v.x, a4v.y, a4v.z, a4v.w};
      float bb[4] = {b4.x, b4.y, b4.z, b4.w};
      #pragma unroll
      for (int i = 0; i < 4; ++i)
        #pragma unroll
        for (int j = 0; j < 4; ++j) acc[i][j] += a[i] * bb[j];
    }
    __syncthreads();
  }
  #pragma unroll
  for (int i = 0; i < 4; ++i)
    *(float4*)&Ct[ty * 4 + i][tx * 4] =
        make_float4(acc[i][0], acc[i][1], acc[i][2], acc[i][3]);
  __syncthreads();
  const int lane = tid & 63, wid = tid >> 6;
  for (int m = wid; m < 64; m += 4) {
    float v = Ct[m][lane] + sbn[lane];
    float s1 = wall_sum(v);
    float s2 = wall_sum(v * v);
    float mu = s1 * (1.f / 64.f);
    float var = s2 * (1.f / 64.f) - mu * mu;
    float o = (v - mu) * rsqrtf(var + 1e-5f) * sg[lane] + sbt[lane];
    h1[(size_t)b * NN * FIN + (size_t)(n0 + m) * FIN + lane] = fmaxf(o, 0.f);
  }
}

// ------------------------------------------------------------
// k_xw1: per scenario — GRU1 once + xwl[s][n][2] = h1[n]·Wn1^T, bns→ws
// ------------------------------------------------------------
__global__ __launch_bounds__(256) void k_xw1(
    const float* __restrict__ h1,
    const float* __restrict__ P1, const float* __restrict__ gh1,
    const float* __restrict__ bih1,
    const float* __restrict__ W1, const float* __restrict__ b1,
    float* __restrict__ xwl_g, float* __restrict__ bns_g) {
  const int s = blockIdx.x;
  const int tid = threadIdx.x;
  const int ln = tid & 63, wv = tid >> 6;
  __shared__ float w0s[64], w1s[64];
  if (tid < H1S) {
    const int j = tid;
    float ir = bih1[j], iz = bih1[H1S + j], in_ = bih1[2 * H1S + j];
    #pragma unroll
    for (int kc = 0; kc < 16; ++kc) {
      const float* Pc = P1 + kc * (M1 * NB);
      ir  += Pc[j * NB + s];
      iz  += Pc[(H1S + j) * NB + s];
      in_ += Pc[(2 * H1S + j) * NB + s];
    }
    float r = sigm(ir + gh1[j]);
    float z = sigm(iz + gh1[H1S + j]);
    float n = tanhf(in_ + r * gh1[2 * H1S + j]);
    float hv = (j < 128) ? W1[j] : b1[j - 128];
    float hnv = (1.f - z) * n + z * hv;
    if (j < 64) w0s[j] = hnv;
    else if (j < 128) w1s[j - 64] = hnv;
    else bns_g[s * 2 + (j - 128)] = hnv;
  }
  __syncthreads();
  const float* h1b = h1 + (size_t)s * NN * FIN;
  float* xo = xwl_g + (size_t)s * NN * 2;
  for (int n = wv * 128; n < wv * 128 + 128; ++n) {
    float v = h1b[n * FIN + ln];
    float s0 = wred_sum(v * w0s[ln]);
    float s1 = wred_sum(v * w1s[ln]);
    if (ln == 0) { xo[n * 2] = s0; xo[n * 2 + 1] = s1; }
  }
}

// ------------------------------------------------------------
// k_aout: out[s][c][:] = A[s][c][:] @ xwl[s] + bns[s]
// 2048 blocks: 32 chunks x 16 rows per scenario. Same per-row math
// and reduction order as r16's k_gcnout second phase.
// ------------------------------------------------------------
__global__ __launch_bounds__(256) void k_aout(
    const float* __restrict__ Adj, const float* __restrict__ xwl_g,
    const float* __restrict__ bns_g, float* __restrict__ out) {
  const int s = blockIdx.x >> 5, q = blockIdx.x & 31;
  const int tid = threadIdx.x;
  const int ln = tid & 63, wv = tid >> 6;
  __shared__ float xwl[NN * 2];
  __shared__ float bns[2];
  {
    const float4* src = (const float4*)(xwl_g + (size_t)s * NN * 2);
    ((float4*)xwl)[tid] = src[tid];
    if (tid < 2) bns[tid] = bns_g[s * 2 + tid];
  }
  __syncthreads();
  const float* Ab = Adj + (size_t)s * NN * NN;
  for (int i = 0; i < 4; ++i) {
    int c = q * 16 + wv * 4 + i;
    const float* Ar = Ab + (size_t)c * NN;
    float a0 = 0.f, a1 = 0.f;
    #pragma unroll
    for (int j = 0; j < 8; ++j) {
      int r = ln + j * 64;
      float av = Ar[r];
      a0 += av * xwl[r * 2]; a1 += av * xwl[r * 2 + 1];
    }
    a0 = wred_sum(a0); a1 = wred_sum(a1);
    if (ln == 0) {
      out[(size_t)s * NN * 2 + c * 2]     = a0 + bns[0];
      out[(size_t)s * NN * 2 + c * 2 + 1] = a1 + bns[1];
    }
  }
}

// ============================================================
extern "C" void kernel_launch(void* const* d_in, const int* in_sizes, int n_in,
                              void* d_out, int out_size, void* d_ws, size_t ws_size,
                              hipStream_t stream) {
  const float* x    = (const float*)d_in[0];
  const int*   ei   = (const int*)  d_in[1];
  const float* ew   = (const float*)d_in[2];
  const float* p0   = (const float*)d_in[3];
  const float* p1   = (const float*)d_in[4];
  const float* W0   = (const float*)d_in[5];
  const float* b0   = (const float*)d_in[6];
  const float* W1   = (const float*)d_in[7];
  const float* b1   = (const float*)d_in[8];
  const float* lng  = (const float*)d_in[9];
  const float* lnb  = (const float*)d_in[10];
  const float* Wih0 = (const float*)d_in[11];
  const float* Whh0 = (const float*)d_in[12];
  const float* bih0 = (const float*)d_in[13];
  const float* bhh0 = (const float*)d_in[14];
  const float* Wih1 = (const float*)d_in[15];
  const float* Whh1 = (const float*)d_in[16];
  const float* bih1 = (const float*)d_in[17];
  const float* bhh1 = (const float*)d_in[18];

  float* ws = (float*)d_ws;
  float* P0    = ws + 0;          // 4*12480*64 = 3,194,880 (P1: 16*390*64)
  float* P1    = ws + 0;
  float* gh0   = ws + 3194880;    // 12,480
  float* gh1   = ws + 3207360;    // 448
  float* Zt0   = ws + 3207808;    // 262,144
  float* Zt1   = ws + 3207808;
  float* hn0   = ws + 3469952;    // 266,240
  float* xw0   = ws + 3744512;    // 2,097,152
  float* h1    = ws + 5841664;    // 2,097,152
  float* dinv  = ws + 7938816;    // 32,768
  float* A     = ws + 7971584;    // 16,777,216
  float* xwl_g = ws + 24748800;   // 65,536
  float* bns_g = ws + 24814336;   // 128 (end 24,814,464 floats = 99.3 MB)
  float* out   = (float*)d_out;

  k_misc  <<<13218, 256, 0, stream>>>(Whh1, bhh1, W1, b1, ei, ew, x, p0,
                                      gh1, A, dinv, Zt0,
                                      Whh0, bhh0, W0, b0, gh0);
  k_big   <<<1036, 256, 0, stream>>>(Wih0, Zt0, P0, ei, ew, dinv, A);
  k_gru0  <<<1040, 256, 0, stream>>>(P0, gh0, bih0, W0, b0, hn0);
  k_xw    <<<dim3(8, 64), 256, 0, stream>>>(x, hn0, xw0);
  k_gcnmm <<<dim3(8, 64), 256, 0, stream>>>(A, xw0, hn0, lng, lnb, h1);
  k_sum   <<<64, 256, 0, stream>>>(h1, p1, Zt1);
  k_gemm_f32<<<dim3(7, 16), 256, 0, stream>>>(Wih1, Zt1, P1, M1, 256);
  k_xw1   <<<64, 256, 0, stream>>>(h1, P1, gh1, bih1, W1, b1, xwl_g, bns_g);
  k_aout  <<<2048, 256, 0, stream>>>(A, xwl_g, bns_g, out);
}